// Round 6
// baseline (577.022 us; speedup 1.0000x reference)
//
#include <hip/hip_runtime.h>

#define HH 51
#define TT 256
#define NB 16
#define USTG 20          // gate-buffer u-stride in dwords (16 batch + 4 pad)

typedef __attribute__((ext_vector_type(8))) __bf16 bf16x8;
typedef __attribute__((ext_vector_type(4))) float  floatx4;

#define MFMA16(A,B,C) __builtin_amdgcn_mfma_f32_16x16x32_bf16((A),(B),(C),0,0,0)

__device__ __forceinline__ float rcp_fast(float x) { return __builtin_amdgcn_rcpf(x); }
// exp2-based, clamp-free: saturates correctly via rcp(inf)=0 / rcp(1)=1
__device__ __forceinline__ float sigm(float x) {
    return rcp_fast(1.0f + exp2f(-1.442695041f * x));
}
__device__ __forceinline__ float tanh_fast(float x) {
    return 1.0f - 2.0f * rcp_fast(1.0f + exp2f(2.885390082f * x));
}
__device__ __forceinline__ unsigned short f2bf(float f) {
    unsigned u = __float_as_uint(f);
    unsigned r = (u + 0x7FFFu + ((u >> 16) & 1u)) >> 16;
    return (unsigned short)r;
}
__device__ __forceinline__ float bf2f(unsigned short h) {
    return __uint_as_float(((unsigned)h) << 16);
}

// ------------- weight pre-pack (identical layout to rounds 4/5) ----------
// B-frag 16x16x32: lane holds B[k=(lane>>4)*8+jj][n=lane&15].
// ids: cell1 ((g*4+U)*2+s)*2+hl (64) | cell2 64+((g*4+U)*4+s)*2+hl (128) |
//      head 192+s*2+hl (4). ws = 196*64*16 B.
__global__ void lstm_prep(const float* __restrict__ Whh1,
                          const float* __restrict__ Wih2, const float* __restrict__ Whh2,
                          const float* __restrict__ Wlin,
                          uint4* __restrict__ frags) {
    int tid = blockIdx.x * blockDim.x + threadIdx.x;
    if (tid >= 196 * 64) return;
    int f = tid >> 6, lane = tid & 63;
    int n = lane & 15, qq = lane >> 4;
    int hl, s, tau, cell;
    if (f < 64)       { cell = 1; int r = f;       hl = r & 1; r >>= 1; s = r & 1; tau = r >> 1; }
    else if (f < 192) { cell = 2; int r = f - 64;  hl = r & 1; r >>= 1; s = r & 3; tau = r >> 2; }
    else              { cell = 3; int r = f - 192; hl = r & 1; s = r >> 1; tau = 0; }
    int g = tau >> 2, U = tau & 3, u = U * 16 + n;
    unsigned int dw[4];
    for (int d = 0; d < 4; d++) {
        unsigned int packed = 0;
        for (int e = 0; e < 2; e++) {
            int jj = d * 2 + e;
            int k = s * 32 + qq * 8 + jj;
            float val = 0.f;
            if (cell == 1) {
                if (u < HH && k < HH) val = Whh1[(g * HH + u) * HH + k];
            } else if (cell == 2) {
                if (u < HH) {
                    if (k < 64) { if (k < HH) val = Wih2[(g * HH + u) * HH + k]; }
                    else        { int k2 = k - 64; if (k2 < HH) val = Whh2[(g * HH + u) * HH + k2]; }
                }
            } else {
                if (n == 0 && k < HH) val = Wlin[k];
            }
            unsigned short hi = f2bf(val);
            unsigned short bits = hl ? f2bf(val - bf2f(hi)) : hi;
            packed |= ((unsigned int)bits) << (16 * e);
        }
        dw[d] = packed;
    }
    frags[f * 64 + lane] = make_uint4(dw[0], dw[1], dw[2], dw[3]);
}

// -------------------------------------------------------------------------
// Role-balanced producer-consumer LSTM. 512 thr = 8 waves, 1 WG/CU.
// Phase A(it): waves 0-3 cell2(it-1) MFMA -> g2 | waves 4-7 update1(it)->h1
// Phase B(it): waves 4-7 cell1(it+1) MFMA -> g1 | waves 0-3 update2(it-1)->h2
//              wave 0 additionally head -> out(it-2)
// Every SIMD hosts one MFMA-heavy and one VALU-heavy wave per phase.
// Update ownership: thread owns 1 u (= role-base + lane>>2) x 4 b
//   ((lane&3)*4 ..+3); gate reads = 1 ds_read_b128 per gate (conflict-free
//   uniform 8/bank); c-state in registers (c1 on waves 4-7, c2 on 0-3).
// Gates carry bias via MFMA accumulator init -> update does no bias add.
// Zero-padding invariant: u in [51,64) has all-zero weights+bias ->
//   gates==0 -> cn=0.5*0+0.5*0=0, h=0.5*tanh(0)=0 -> h stays exactly 0.
// -------------------------------------------------------------------------
__launch_bounds__(512, 2)
__global__ void lstm_main(const float* __restrict__ input,
                          const uint4* __restrict__ frags,
                          const float* __restrict__ Wih1,
                          const float* __restrict__ bih1, const float* __restrict__ bhh1,
                          const float* __restrict__ bih2, const float* __restrict__ bhh2,
                          const float* __restrict__ blin,
                          float* __restrict__ out) {
    __shared__ __align__(16) unsigned int h1h[2][16][36], h1l[2][16][36];
    __shared__ __align__(16) unsigned int h2h[2][16][36], h2l[2][16][36];
    __shared__ __align__(16) float g1buf[4 * 64 * USTG];
    __shared__ __align__(16) float g2buf[4 * 64 * USTG];
    __shared__ float xb[16 * 257];

    const int tid  = threadIdx.x;
    const int lane = tid & 63;
    const int w    = tid >> 6;
    const int l15  = lane & 15;
    const int q    = lane >> 4;
    const int b0g  = blockIdx.x * NB;
    const bool mf  = (w < 4);

    for (int i = tid; i < 2 * 16 * 36; i += 512) {
        ((unsigned*)h1h)[i] = 0; ((unsigned*)h1l)[i] = 0;
        ((unsigned*)h2h)[i] = 0; ((unsigned*)h2l)[i] = 0;
    }
    for (int c = 0; c < 2; c++) {
        int flat = (tid + c * 512) * 4;
        int b = flat >> 8, t0 = flat & 255;
        float4 v = *(const float4*)&input[(size_t)(b0g + b) * TT + t0];
        xb[b * 257 + t0 + 0] = v.x; xb[b * 257 + t0 + 1] = v.y;
        xb[b * 257 + t0 + 2] = v.z; xb[b * 257 + t0 + 3] = v.w;
    }

    // Weight-stationary fragments (union across roles; B-operands may live
    // in AGPRs on gfx950's unified file).
    bf16x8 fr[36];
    float bcol[4], wxv[4];
    if (mf) {
        // cell2, gate g = w, tiles U=0..3
#pragma unroll
        for (int U = 0; U < 4; U++) {
            int tau = w * 4 + U;
#pragma unroll
            for (int s = 0; s < 4; s++) {
                fr[U * 8 + s * 2 + 0] = __builtin_bit_cast(bf16x8, frags[(64 + (tau * 4 + s) * 2 + 0) * 64 + lane]);
                fr[U * 8 + s * 2 + 1] = __builtin_bit_cast(bf16x8, frags[(64 + (tau * 4 + s) * 2 + 1) * 64 + lane]);
            }
            int uc = U * 16 + l15;
            bcol[U] = (uc < HH) ? (bih2[w * HH + uc] + bhh2[w * HH + uc]) : 0.f;
            wxv[U] = 0.f;
        }
        if (w == 0) {
#pragma unroll
            for (int s = 0; s < 2; s++) {
                fr[32 + s * 2 + 0] = __builtin_bit_cast(bf16x8, frags[(192 + s * 2 + 0) * 64 + lane]);
                fr[32 + s * 2 + 1] = __builtin_bit_cast(bf16x8, frags[(192 + s * 2 + 1) * 64 + lane]);
            }
        }
    } else {
        // cell1, gate g = w-4, tiles U=0..3
        int g = w - 4;
#pragma unroll
        for (int U = 0; U < 4; U++) {
            int tau = g * 4 + U;
#pragma unroll
            for (int s = 0; s < 2; s++) {
                fr[U * 4 + s * 2 + 0] = __builtin_bit_cast(bf16x8, frags[((tau * 2 + s) * 2 + 0) * 64 + lane]);
                fr[U * 4 + s * 2 + 1] = __builtin_bit_cast(bf16x8, frags[((tau * 2 + s) * 2 + 1) * 64 + lane]);
            }
            int uc = U * 16 + l15;
            bcol[U] = (uc < HH) ? (bih1[g * HH + uc] + bhh1[g * HH + uc]) : 0.f;
            wxv[U]  = (uc < HH) ? Wih1[g * HH + uc] : 0.f;
        }
    }
    const float bl = blin[0];

    // update ownership: 1 u x 4 b; c1 on upd waves, c2 on mf waves
    const int gu = (mf ? w : (w - 4)) * 16 + (lane >> 2);   // owned u, 0..63
    const int gb = (lane & 3) * 4;                          // first of 4 b's
    float cst[4] = {0.f, 0.f, 0.f, 0.f};

    __syncthreads();

    // prologue: g1(0) = x(0)*Wih1 + b1  (h1(-1)=0 -> no MFMA term)
    if (!mf) {
        float xr[4];
#pragma unroll
        for (int r = 0; r < 4; r++) xr[r] = xb[(q * 4 + r) * 257 + 0];
#pragma unroll
        for (int U = 0; U < 4; U++) {
            floatx4 a;
#pragma unroll
            for (int r = 0; r < 4; r++) a[r] = fmaf(xr[r], wxv[U], bcol[U]);
            *(floatx4*)&g1buf[((w - 4) * 64 + U * 16 + l15) * USTG + q * 4] = a;
        }
    }
    __syncthreads();

    for (int it = 0; it <= TT + 1; it++) {
        // ================= PHASE A =================
        if (mf) {
            if (it >= 1 && it <= TT) {          // cell2(it-1) -> g2buf
                const int ph1 = (it - 1) & 1;   // h1(it-1)
                const int ph2 = it & 1;         // h2(it-2)
                floatx4 d[4];
#pragma unroll
                for (int U = 0; U < 4; U++)
                    d[U] = (floatx4){bcol[U], bcol[U], bcol[U], bcol[U]};
#pragma unroll
                for (int s = 0; s < 4; s++) {
                    int base = ((s & 1) * 16 + q * 4 + 4 * (l15 >> 1)) & 31;
                    bf16x8 ah, al;
                    if (s < 2) { ah = *(const bf16x8*)&h1h[ph1][l15][base];
                                 al = *(const bf16x8*)&h1l[ph1][l15][base]; }
                    else       { ah = *(const bf16x8*)&h2h[ph2][l15][base];
                                 al = *(const bf16x8*)&h2l[ph2][l15][base]; }
#pragma unroll
                    for (int U = 0; U < 4; U++) {
                        d[U] = MFMA16(ah, fr[U * 8 + s * 2 + 0], d[U]);
                        d[U] = MFMA16(ah, fr[U * 8 + s * 2 + 1], d[U]);
                        d[U] = MFMA16(al, fr[U * 8 + s * 2 + 0], d[U]);
                    }
                }
#pragma unroll
                for (int U = 0; U < 4; U++)
                    *(floatx4*)&g2buf[(w * 64 + U * 16 + l15) * USTG + q * 4] = d[U];
            }
        } else {
            if (it <= TT - 1) {                 // update1(it) -> h1[it&1]
                const int ph = it & 1;
                floatx4 G[4];
#pragma unroll
                for (int g = 0; g < 4; g++)
                    G[g] = *(const floatx4*)&g1buf[(g * 64 + gu) * USTG + gb];
#pragma unroll
                for (int r = 0; r < 4; r++) {
                    float cn = fmaf(sigm(G[1][r]), cst[r], sigm(G[0][r]) * tanh_fast(G[2][r]));
                    cst[r] = cn;
                    float h = sigm(G[3][r]) * tanh_fast(cn);
                    unsigned hb = __float_as_uint(h);
                    unsigned short hi = (unsigned short)(hb >> 16);
                    float lof = h - __uint_as_float(hb & 0xFFFF0000u);
                    unsigned short lo = (unsigned short)(__float_as_uint(lof) >> 16);
                    int bb = gb + r;
                    int widx = (((gu >> 1) + 4 * (bb >> 1)) & 31) * 2 + (gu & 1);
                    ((unsigned short*)&h1h[ph][bb][0])[widx] = hi;
                    ((unsigned short*)&h1l[ph][bb][0])[widx] = lo;
                }
            }
        }
        __syncthreads();

        // ================= PHASE B =================
        if (!mf) {
            if (it <= TT - 2) {                 // cell1(it+1) -> g1buf
                const int ph = it & 1;          // h1(it)
                float xr[4];
#pragma unroll
                for (int r = 0; r < 4; r++) xr[r] = xb[(q * 4 + r) * 257 + it + 1];
                floatx4 a[4];
#pragma unroll
                for (int U = 0; U < 4; U++)
#pragma unroll
                    for (int r = 0; r < 4; r++) a[U][r] = fmaf(xr[r], wxv[U], bcol[U]);
#pragma unroll
                for (int s = 0; s < 2; s++) {
                    int base = (s * 16 + q * 4 + 4 * (l15 >> 1)) & 31;
                    bf16x8 ah = *(const bf16x8*)&h1h[ph][l15][base];
                    bf16x8 al = *(const bf16x8*)&h1l[ph][l15][base];
#pragma unroll
                    for (int U = 0; U < 4; U++) {
                        a[U] = MFMA16(ah, fr[U * 4 + s * 2 + 0], a[U]);
                        a[U] = MFMA16(ah, fr[U * 4 + s * 2 + 1], a[U]);
                        a[U] = MFMA16(al, fr[U * 4 + s * 2 + 0], a[U]);
                    }
                }
#pragma unroll
                for (int U = 0; U < 4; U++)
                    *(floatx4*)&g1buf[((w - 4) * 64 + U * 16 + l15) * USTG + q * 4] = a[U];
            }
        } else {
            if (it >= 1 && it <= TT) {          // update2(it-1) -> h2[(it-1)&1]
                const int ph = (it - 1) & 1;
                floatx4 G[4];
#pragma unroll
                for (int g = 0; g < 4; g++)
                    G[g] = *(const floatx4*)&g2buf[(g * 64 + gu) * USTG + gb];
#pragma unroll
                for (int r = 0; r < 4; r++) {
                    float cn = fmaf(sigm(G[1][r]), cst[r], sigm(G[0][r]) * tanh_fast(G[2][r]));
                    cst[r] = cn;
                    float h = sigm(G[3][r]) * tanh_fast(cn);
                    unsigned hb = __float_as_uint(h);
                    unsigned short hi = (unsigned short)(hb >> 16);
                    float lof = h - __uint_as_float(hb & 0xFFFF0000u);
                    unsigned short lo = (unsigned short)(__float_as_uint(lof) >> 16);
                    int bb = gb + r;
                    int widx = (((gu >> 1) + 4 * (bb >> 1)) & 31) * 2 + (gu & 1);
                    ((unsigned short*)&h2h[ph][bb][0])[widx] = hi;
                    ((unsigned short*)&h2l[ph][bb][0])[widx] = lo;
                }
            }
            if (w == 0 && it >= 2) {            // head: out(it-2) = Wlin.h2(it-2)+bl
                const int ph = it & 1;          // (it-2)&1
                floatx4 ho = {0.f, 0.f, 0.f, 0.f};
#pragma unroll
                for (int s = 0; s < 2; s++) {
                    int base = (s * 16 + q * 4 + 4 * (l15 >> 1)) & 31;
                    bf16x8 ah = *(const bf16x8*)&h2h[ph][l15][base];
                    bf16x8 al = *(const bf16x8*)&h2l[ph][l15][base];
                    ho = MFMA16(ah, fr[32 + s * 2 + 0], ho);
                    ho = MFMA16(ah, fr[32 + s * 2 + 1], ho);
                    ho = MFMA16(al, fr[32 + s * 2 + 0], ho);
                }
                if (l15 == 0) {
#pragma unroll
                    for (int r = 0; r < 4; r++)
                        out[(size_t)(b0g + q * 4 + r) * TT + (it - 2)] = ho[r] + bl;
                }
            }
        }
        __syncthreads();
    }
}

extern "C" void kernel_launch(void* const* d_in, const int* in_sizes, int n_in,
                              void* d_out, int out_size, void* d_ws, size_t ws_size,
                              hipStream_t stream) {
    const float* input = (const float*)d_in[0];
    const float* Wih1  = (const float*)d_in[1];
    const float* Whh1  = (const float*)d_in[2];
    const float* bih1  = (const float*)d_in[3];
    const float* bhh1  = (const float*)d_in[4];
    const float* Wih2  = (const float*)d_in[5];
    const float* Whh2  = (const float*)d_in[6];
    const float* bih2  = (const float*)d_in[7];
    const float* bhh2  = (const float*)d_in[8];
    const float* Wlin  = (const float*)d_in[9];
    const float* blin  = (const float*)d_in[10];

    uint4* frags = (uint4*)d_ws;            // 196 frags * 1 KiB
    int B = in_sizes[0] / TT;               // 4096

    lstm_prep<<<49, 256, 0, stream>>>(Whh1, Wih2, Whh2, Wlin, frags);
    lstm_main<<<B / NB, 512, 0, stream>>>(input, frags, Wih1, bih1, bhh1,
                                          bih2, bhh2, blin, (float*)d_out);
}

// Round 7
// 417.566 us; speedup vs baseline: 1.3819x; 1.3819x over previous
//
#include <hip/hip_runtime.h>

#define HH 51
#define TT 256
#define NB 16

typedef __attribute__((ext_vector_type(8))) __bf16 bf16x8;
typedef __attribute__((ext_vector_type(4))) float  floatx4;

#define MFMA16(A,B,C) __builtin_amdgcn_mfma_f32_16x16x32_bf16((A),(B),(C),0,0,0)

__device__ __forceinline__ float rcp_fast(float x) { return __builtin_amdgcn_rcpf(x); }
#if __has_builtin(__builtin_amdgcn_exp2f)
__device__ __forceinline__ float exp2_fast(float x) { return __builtin_amdgcn_exp2f(x); }
#else
__device__ __forceinline__ float exp2_fast(float x) { return __expf(0.69314718056f * x); }
#endif
// native-rate, clamp-free (saturates via rcp(inf)=0)
__device__ __forceinline__ float sigm(float x) {
    return rcp_fast(1.0f + exp2_fast(-1.442695041f * x));
}
__device__ __forceinline__ float tanh_fast(float x) {
    return 1.0f - 2.0f * rcp_fast(1.0f + exp2_fast(2.885390082f * x));
}
__device__ __forceinline__ unsigned short f2bf(float f) {
    unsigned u = __float_as_uint(f);
    unsigned r = (u + 0x7FFFu + ((u >> 16) & 1u)) >> 16;
    return (unsigned short)r;
}
__device__ __forceinline__ float bf2f(unsigned short h) {
    return __uint_as_float(((unsigned)h) << 16);
}

// ------------- weight pre-pack (identical layout to rounds 4-6) ----------
// B-frag 16x16x32: lane holds B[k=(lane>>4)*8+jj][n=lane&15].
// ids: cell1 ((g*4+U)*2+s)*2+hl (64) | cell2 64+((g*4+U)*4+s)*2+hl (128) |
//      head 192+s*2+hl (4). ws = 196*64*16 B.
__global__ void lstm_prep(const float* __restrict__ Whh1,
                          const float* __restrict__ Wih2, const float* __restrict__ Whh2,
                          const float* __restrict__ Wlin,
                          uint4* __restrict__ frags) {
    int tid = blockIdx.x * blockDim.x + threadIdx.x;
    if (tid >= 196 * 64) return;
    int f = tid >> 6, lane = tid & 63;
    int n = lane & 15, qq = lane >> 4;
    int hl, s, tau, cell;
    if (f < 64)       { cell = 1; int r = f;       hl = r & 1; r >>= 1; s = r & 1; tau = r >> 1; }
    else if (f < 192) { cell = 2; int r = f - 64;  hl = r & 1; r >>= 1; s = r & 3; tau = r >> 2; }
    else              { cell = 3; int r = f - 192; hl = r & 1; s = r >> 1; tau = 0; }
    int g = tau >> 2, U = tau & 3, u = U * 16 + n;
    unsigned int dw[4];
    for (int d = 0; d < 4; d++) {
        unsigned int packed = 0;
        for (int e = 0; e < 2; e++) {
            int jj = d * 2 + e;
            int k = s * 32 + qq * 8 + jj;
            float val = 0.f;
            if (cell == 1) {
                if (u < HH && k < HH) val = Whh1[(g * HH + u) * HH + k];
            } else if (cell == 2) {
                if (u < HH) {
                    if (k < 64) { if (k < HH) val = Wih2[(g * HH + u) * HH + k]; }
                    else        { int k2 = k - 64; if (k2 < HH) val = Whh2[(g * HH + u) * HH + k2]; }
                }
            } else {
                if (n == 0 && k < HH) val = Wlin[k];
            }
            unsigned short hi = f2bf(val);
            unsigned short bits = hl ? f2bf(val - bf2f(hi)) : hi;
            packed |= ((unsigned int)bits) << (16 * e);
        }
        dw[d] = packed;
    }
    frags[f * 64 + lane] = make_uint4(dw[0], dw[1], dw[2], dw[3]);
}

// -------------------------------------------------------------------------
// One-barrier skewed LSTM. 512 thr = 8 waves, 1 WG = 16 batch, 1 WG/CU.
// Wave w<4  (cell2): owns u-tile U=w, ALL 4 gates of cell2. Per it in [1,TT]:
//   48 MFMA over [h1(it-1) | h2(it-2)] -> gates in ACC (bias in C-init),
//   in-register activation (c2 in VGPRs), write h2(it-1) -> h2[(it-1)&1].
// Wave w>=4 (cell1): owns u-tile U=w-4. Per it in [0,TT-1]:
//   24 MFMA over h1(it-1) + x(it)*Wih1 -> update -> h1(it) -> h1[it&1].
//   Wave 4 extra: head MFMA over h2[it&1]=h2(it-2) -> out(it-2), it in [2,TT+1].
// All reads hit parities written in PREVIOUS iterations -> ONE barrier/step.
// NO gate LDS round-trip: activation straight from accumulator.
// C/D (m89): col=lane&15=u, row=q*4+r=b. A-frag (m120): lane=b, k=q*8+j.
// h layout: uint[2][16][36], swizzled (round-6-verified):
//   write widx = (((u>>1)+4*(b>>1))&31)*2 + (u&1)  (ushort idx)
//   read  base = (ks*16 + q*4 + 4*(l15>>1)) & 31   (uint idx, 16B load)
// Zero-pad invariant: u in [51,64) has zero weights+bias -> h stays 0.
// -------------------------------------------------------------------------
__launch_bounds__(512, 2)
__global__ void lstm_main(const float* __restrict__ input,
                          const uint4* __restrict__ frags,
                          const float* __restrict__ Wih1,
                          const float* __restrict__ bih1, const float* __restrict__ bhh1,
                          const float* __restrict__ bih2, const float* __restrict__ bhh2,
                          const float* __restrict__ blin,
                          float* __restrict__ out) {
    __shared__ __align__(16) unsigned int h1h[2][16][36], h1l[2][16][36];
    __shared__ __align__(16) unsigned int h2h[2][16][36], h2l[2][16][36];
    __shared__ float xb[16 * 257];

    const int tid  = threadIdx.x;
    const int lane = tid & 63;
    const int w    = tid >> 6;
    const int l15  = lane & 15;
    const int q    = lane >> 4;
    const int b0g  = blockIdx.x * NB;
    const bool c2w = (w < 4);
    const int U    = c2w ? w : (w - 4);
    const int uc   = U * 16 + l15;             // owned u (col in C-layout)
    const bool uok = (uc < HH);

    for (int i = tid; i < 2 * 16 * 36; i += 512) {
        ((unsigned*)h1h)[i] = 0; ((unsigned*)h1l)[i] = 0;
        ((unsigned*)h2h)[i] = 0; ((unsigned*)h2l)[i] = 0;
    }
    for (int c = 0; c < 2; c++) {
        int flat = (tid + c * 512) * 4;
        int b = flat >> 8, t0 = flat & 255;
        float4 v = *(const float4*)&input[(size_t)(b0g + b) * TT + t0];
        xb[b * 257 + t0 + 0] = v.x; xb[b * 257 + t0 + 1] = v.y;
        xb[b * 257 + t0 + 2] = v.z; xb[b * 257 + t0 + 3] = v.w;
    }

    // Weight-stationary fragments. cell2 wave: fr[g*8+s*2+hl] (32 frags).
    // cell1 wave: fr[g*4+s*2+hl] (16); wave 4 head: fr[16+s*2+hl] (4).
    bf16x8 fr[32];
    float bcol[4], wx[4];
    if (c2w) {
#pragma unroll
        for (int g = 0; g < 4; g++) {
            int tau = g * 4 + U;
#pragma unroll
            for (int s = 0; s < 4; s++) {
                fr[g * 8 + s * 2 + 0] = __builtin_bit_cast(bf16x8, frags[(64 + (tau * 4 + s) * 2 + 0) * 64 + lane]);
                fr[g * 8 + s * 2 + 1] = __builtin_bit_cast(bf16x8, frags[(64 + (tau * 4 + s) * 2 + 1) * 64 + lane]);
            }
            bcol[g] = uok ? (bih2[g * HH + uc] + bhh2[g * HH + uc]) : 0.f;
            wx[g] = 0.f;
        }
    } else {
#pragma unroll
        for (int g = 0; g < 4; g++) {
            int tau = g * 4 + U;
#pragma unroll
            for (int s = 0; s < 2; s++) {
                fr[g * 4 + s * 2 + 0] = __builtin_bit_cast(bf16x8, frags[((tau * 2 + s) * 2 + 0) * 64 + lane]);
                fr[g * 4 + s * 2 + 1] = __builtin_bit_cast(bf16x8, frags[((tau * 2 + s) * 2 + 1) * 64 + lane]);
            }
            bcol[g] = uok ? (bih1[g * HH + uc] + bhh1[g * HH + uc]) : 0.f;
            wx[g]   = uok ? Wih1[g * HH + uc] : 0.f;
        }
        if (w == 4) {
#pragma unroll
            for (int s = 0; s < 2; s++) {
                fr[16 + s * 2 + 0] = __builtin_bit_cast(bf16x8, frags[(192 + s * 2 + 0) * 64 + lane]);
                fr[16 + s * 2 + 1] = __builtin_bit_cast(bf16x8, frags[(192 + s * 2 + 1) * 64 + lane]);
            }
        }
    }
    const float bl = blin[0];
    float cst[4] = {0.f, 0.f, 0.f, 0.f};      // c2 on waves 0-3, c1 on 4-7

    __syncthreads();

    for (int it = 0; it <= TT + 1; it++) {
        if (c2w) {
            if (it >= 1 && it <= TT) {        // cell2: h2(it-1)
                const int ph1 = (it + 1) & 1; // h1(it-1)
                const int ph2 = it & 1;       // h2(it-2)
                const int pw  = (it + 1) & 1; // write h2(it-1)
                floatx4 d[4];
#pragma unroll
                for (int g = 0; g < 4; g++)
                    d[g] = (floatx4){bcol[g], bcol[g], bcol[g], bcol[g]};
#pragma unroll
                for (int s = 0; s < 4; s++) {
                    int base = ((s & 1) * 16 + q * 4 + 4 * (l15 >> 1)) & 31;
                    bf16x8 ah, al;
                    if (s < 2) { ah = *(const bf16x8*)&h1h[ph1][l15][base];
                                 al = *(const bf16x8*)&h1l[ph1][l15][base]; }
                    else       { ah = *(const bf16x8*)&h2h[ph2][l15][base];
                                 al = *(const bf16x8*)&h2l[ph2][l15][base]; }
#pragma unroll
                    for (int g = 0; g < 4; g++) {
                        d[g] = MFMA16(ah, fr[g * 8 + s * 2 + 0], d[g]);
                        d[g] = MFMA16(ah, fr[g * 8 + s * 2 + 1], d[g]);
                        d[g] = MFMA16(al, fr[g * 8 + s * 2 + 0], d[g]);
                    }
                }
#pragma unroll
                for (int r = 0; r < 4; r++) {
                    float cn = fmaf(sigm(d[1][r]), cst[r], sigm(d[0][r]) * tanh_fast(d[2][r]));
                    cst[r] = cn;
                    float h = sigm(d[3][r]) * tanh_fast(cn);
                    unsigned hb = __float_as_uint(h);
                    unsigned short hi = (unsigned short)(hb >> 16);
                    float lof = h - __uint_as_float(hb & 0xFFFF0000u);
                    unsigned short lo = (unsigned short)(__float_as_uint(lof) >> 16);
                    int bb = q * 4 + r;
                    int widx = (((uc >> 1) + 4 * (bb >> 1)) & 31) * 2 + (uc & 1);
                    ((unsigned short*)&h2h[pw][bb][0])[widx] = hi;
                    ((unsigned short*)&h2l[pw][bb][0])[widx] = lo;
                }
            }
        } else {
            if (it <= TT - 1) {               // cell1: h1(it)
                const int phr = (it + 1) & 1; // h1(it-1)
                const int phw = it & 1;       // write h1(it)
                float xr[4];
#pragma unroll
                for (int r = 0; r < 4; r++) xr[r] = xb[(q * 4 + r) * 257 + it];
                floatx4 a[4];
#pragma unroll
                for (int g = 0; g < 4; g++)
#pragma unroll
                    for (int r = 0; r < 4; r++) a[g][r] = fmaf(xr[r], wx[g], bcol[g]);
#pragma unroll
                for (int s = 0; s < 2; s++) {
                    int base = (s * 16 + q * 4 + 4 * (l15 >> 1)) & 31;
                    bf16x8 ah = *(const bf16x8*)&h1h[phr][l15][base];
                    bf16x8 al = *(const bf16x8*)&h1l[phr][l15][base];
#pragma unroll
                    for (int g = 0; g < 4; g++) {
                        a[g] = MFMA16(ah, fr[g * 4 + s * 2 + 0], a[g]);
                        a[g] = MFMA16(ah, fr[g * 4 + s * 2 + 1], a[g]);
                        a[g] = MFMA16(al, fr[g * 4 + s * 2 + 0], a[g]);
                    }
                }
#pragma unroll
                for (int r = 0; r < 4; r++) {
                    float cn = fmaf(sigm(a[1][r]), cst[r], sigm(a[0][r]) * tanh_fast(a[2][r]));
                    cst[r] = cn;
                    float h = sigm(a[3][r]) * tanh_fast(cn);
                    unsigned hb = __float_as_uint(h);
                    unsigned short hi = (unsigned short)(hb >> 16);
                    float lof = h - __uint_as_float(hb & 0xFFFF0000u);
                    unsigned short lo = (unsigned short)(__float_as_uint(lof) >> 16);
                    int bb = q * 4 + r;
                    int widx = (((uc >> 1) + 4 * (bb >> 1)) & 31) * 2 + (uc & 1);
                    ((unsigned short*)&h1h[phw][bb][0])[widx] = hi;
                    ((unsigned short*)&h1l[phw][bb][0])[widx] = lo;
                }
            }
            if (w == 4 && it >= 2) {          // head: out(it-2) from h2[it&1]
                const int ph = it & 1;
                floatx4 ho = {0.f, 0.f, 0.f, 0.f};
#pragma unroll
                for (int s = 0; s < 2; s++) {
                    int base = (s * 16 + q * 4 + 4 * (l15 >> 1)) & 31;
                    bf16x8 ah = *(const bf16x8*)&h2h[ph][l15][base];
                    bf16x8 al = *(const bf16x8*)&h2l[ph][l15][base];
                    ho = MFMA16(ah, fr[16 + s * 2 + 0], ho);
                    ho = MFMA16(ah, fr[16 + s * 2 + 1], ho);
                    ho = MFMA16(al, fr[16 + s * 2 + 0], ho);
                }
                if (l15 == 0) {
#pragma unroll
                    for (int r = 0; r < 4; r++)
                        out[(size_t)(b0g + q * 4 + r) * TT + (it - 2)] = ho[r] + bl;
                }
            }
        }
        __syncthreads();
    }
}

extern "C" void kernel_launch(void* const* d_in, const int* in_sizes, int n_in,
                              void* d_out, int out_size, void* d_ws, size_t ws_size,
                              hipStream_t stream) {
    const float* input = (const float*)d_in[0];
    const float* Wih1  = (const float*)d_in[1];
    const float* Whh1  = (const float*)d_in[2];
    const float* bih1  = (const float*)d_in[3];
    const float* bhh1  = (const float*)d_in[4];
    const float* Wih2  = (const float*)d_in[5];
    const float* Whh2  = (const float*)d_in[6];
    const float* bih2  = (const float*)d_in[7];
    const float* bhh2  = (const float*)d_in[8];
    const float* Wlin  = (const float*)d_in[9];
    const float* blin  = (const float*)d_in[10];

    uint4* frags = (uint4*)d_ws;            // 196 frags * 1 KiB
    int B = in_sizes[0] / TT;               // 4096

    lstm_prep<<<49, 256, 0, stream>>>(Whh1, Wih2, Whh2, Wlin, frags);
    lstm_main<<<B / NB, 512, 0, stream>>>(input, frags, Wih1, bih1, bhh1,
                                          bih2, bhh2, blin, (float*)d_out);
}

// Round 8
// 386.847 us; speedup vs baseline: 1.4916x; 1.0794x over previous
//
#include <hip/hip_runtime.h>

#define HH 51
#define TT 256
#define NB 16
#define L2E 1.442695041f

typedef __attribute__((ext_vector_type(8))) __bf16 bf16x8;
typedef __attribute__((ext_vector_type(4))) float  floatx4;

#define MFMA16(A,B,C) __builtin_amdgcn_mfma_f32_16x16x32_bf16((A),(B),(C),0,0,0)

__device__ __forceinline__ float rcp_fast(float x) { return __builtin_amdgcn_rcpf(x); }
#if __has_builtin(__builtin_amdgcn_exp2f)
__device__ __forceinline__ float exp2_fast(float x) { return __builtin_amdgcn_exp2f(x); }
#else
__device__ __forceinline__ float exp2_fast(float x) { return __expf(0.69314718056f * x); }
#endif
// Inputs PRE-SCALED by log2(e) (sigmoid args) / 2*log2(e) (tanh args).
// sigm_s(a)=sigma(x) with a=1.4427x ; tanh_s(a)=tanh(x) with a=2.8854x.
// NaN-safe: exp2->inf => rcp->0 => saturate correctly.
__device__ __forceinline__ float sigm_s(float a) {
    return rcp_fast(1.0f + exp2_fast(-a));
}
__device__ __forceinline__ float tanh_s(float a) {
    return fmaf(-2.0f, rcp_fast(1.0f + exp2_fast(a)), 1.0f);
}
__device__ __forceinline__ unsigned short f2bf(float f) {
    unsigned u = __float_as_uint(f);
    unsigned r = (u + 0x7FFFu + ((u >> 16) & 1u)) >> 16;
    return (unsigned short)r;
}
__device__ __forceinline__ float bf2f(unsigned short h) {
    return __uint_as_float(((unsigned)h) << 16);
}

// ------------- weight pre-pack (round-7 layout + gate-scale folding) -----
// B-frag 16x16x32: lane holds B[k=(lane>>4)*8+jj][n=lane&15].
// ids: cell1 ((g*4+U)*2+s)*2+hl (64) | cell2 64+((g*4+U)*4+s)*2+hl (128) |
//      head 192+s*2+hl (4, UNSCALED). ws = 196*64*16 B.
// Gate scale: i,f,o -> *L2E ; g -> *2*L2E (folds the exp2 prescale mul).
__global__ void lstm_prep(const float* __restrict__ Whh1,
                          const float* __restrict__ Wih2, const float* __restrict__ Whh2,
                          const float* __restrict__ Wlin,
                          uint4* __restrict__ frags) {
    int tid = blockIdx.x * blockDim.x + threadIdx.x;
    if (tid >= 196 * 64) return;
    int f = tid >> 6, lane = tid & 63;
    int n = lane & 15, qq = lane >> 4;
    int hl, s, tau, cell;
    if (f < 64)       { cell = 1; int r = f;       hl = r & 1; r >>= 1; s = r & 1; tau = r >> 1; }
    else if (f < 192) { cell = 2; int r = f - 64;  hl = r & 1; r >>= 1; s = r & 3; tau = r >> 2; }
    else              { cell = 3; int r = f - 192; hl = r & 1; s = r >> 1; tau = 0; }
    int g = tau >> 2, U = tau & 3, u = U * 16 + n;
    float sc = (cell == 3) ? 1.0f : ((g == 2) ? 2.0f * L2E : L2E);
    unsigned int dw[4];
    for (int d = 0; d < 4; d++) {
        unsigned int packed = 0;
        for (int e = 0; e < 2; e++) {
            int jj = d * 2 + e;
            int k = s * 32 + qq * 8 + jj;
            float val = 0.f;
            if (cell == 1) {
                if (u < HH && k < HH) val = Whh1[(g * HH + u) * HH + k];
            } else if (cell == 2) {
                if (u < HH) {
                    if (k < 64) { if (k < HH) val = Wih2[(g * HH + u) * HH + k]; }
                    else        { int k2 = k - 64; if (k2 < HH) val = Whh2[(g * HH + u) * HH + k2]; }
                }
            } else {
                if (n == 0 && k < HH) val = Wlin[k];
            }
            val *= sc;
            unsigned short hi = f2bf(val);
            unsigned short bits = hl ? f2bf(val - bf2f(hi)) : hi;
            packed |= ((unsigned int)bits) << (16 * e);
        }
        dw[d] = packed;
    }
    frags[f * 64 + lane] = make_uint4(dw[0], dw[1], dw[2], dw[3]);
}

// -------------------------------------------------------------------------
// One-barrier skewed LSTM (round-7 structure), VALU-dieted:
//  - gate prescale folded into weights/biases (exp2 muls deleted)
//  - loop unrolled x2 -> parity compile-time -> LDS addresses hoisted
//  - x buffer transposed to [t][b] -> one ds_read_b128 per iteration
// Roles/skew/layout identical to round 7 (verified).
// -------------------------------------------------------------------------
__launch_bounds__(512, 2)
__global__ void lstm_main(const float* __restrict__ input,
                          const uint4* __restrict__ frags,
                          const float* __restrict__ Wih1,
                          const float* __restrict__ bih1, const float* __restrict__ bhh1,
                          const float* __restrict__ bih2, const float* __restrict__ bhh2,
                          const float* __restrict__ blin,
                          float* __restrict__ out) {
    __shared__ __align__(16) unsigned int h1h[2][16][36], h1l[2][16][36];
    __shared__ __align__(16) unsigned int h2h[2][16][36], h2l[2][16][36];
    __shared__ __align__(16) float xb[TT * 16];      // [t][b]

    const int tid  = threadIdx.x;
    const int lane = tid & 63;
    const int w    = tid >> 6;
    const int l15  = lane & 15;
    const int q    = lane >> 4;
    const int b0g  = blockIdx.x * NB;
    const bool c2w = (w < 4);
    const int U    = c2w ? w : (w - 4);
    const int uc   = U * 16 + l15;
    const bool uok = (uc < HH);

    for (int i = tid; i < 2 * 16 * 36; i += 512) {
        ((unsigned*)h1h)[i] = 0; ((unsigned*)h1l)[i] = 0;
        ((unsigned*)h2h)[i] = 0; ((unsigned*)h2l)[i] = 0;
    }
    // stage x transposed: read coalesced float4 along t, scatter to [t][b]
    for (int c = 0; c < 2; c++) {
        int flat = tid + c * 512;                    // 1024 float4 rows total
        int b = flat >> 6, t0 = (flat & 63) * 4;
        float4 v = *(const float4*)&input[(size_t)(b0g + b) * TT + t0];
        xb[(t0 + 0) * 16 + b] = v.x; xb[(t0 + 1) * 16 + b] = v.y;
        xb[(t0 + 2) * 16 + b] = v.z; xb[(t0 + 3) * 16 + b] = v.w;
    }

    // weight-stationary fragments (round-7 layout)
    bf16x8 fr[32];
    float bcol[4], wx[4];
    if (c2w) {
#pragma unroll
        for (int g = 0; g < 4; g++) {
            int tau = g * 4 + U;
#pragma unroll
            for (int s = 0; s < 4; s++) {
                fr[g * 8 + s * 2 + 0] = __builtin_bit_cast(bf16x8, frags[(64 + (tau * 4 + s) * 2 + 0) * 64 + lane]);
                fr[g * 8 + s * 2 + 1] = __builtin_bit_cast(bf16x8, frags[(64 + (tau * 4 + s) * 2 + 1) * 64 + lane]);
            }
            float sc = (g == 2) ? 2.0f * L2E : L2E;
            bcol[g] = uok ? (bih2[g * HH + uc] + bhh2[g * HH + uc]) * sc : 0.f;
            wx[g] = 0.f;
        }
    } else {
#pragma unroll
        for (int g = 0; g < 4; g++) {
            int tau = g * 4 + U;
#pragma unroll
            for (int s = 0; s < 2; s++) {
                fr[g * 4 + s * 2 + 0] = __builtin_bit_cast(bf16x8, frags[((tau * 2 + s) * 2 + 0) * 64 + lane]);
                fr[g * 4 + s * 2 + 1] = __builtin_bit_cast(bf16x8, frags[((tau * 2 + s) * 2 + 1) * 64 + lane]);
            }
            float sc = (g == 2) ? 2.0f * L2E : L2E;
            bcol[g] = uok ? (bih1[g * HH + uc] + bhh1[g * HH + uc]) * sc : 0.f;
            wx[g]   = uok ? Wih1[g * HH + uc] * sc : 0.f;
        }
        if (w == 4) {
#pragma unroll
            for (int s = 0; s < 2; s++) {
                fr[16 + s * 2 + 0] = __builtin_bit_cast(bf16x8, frags[(192 + s * 2 + 0) * 64 + lane]);
                fr[16 + s * 2 + 1] = __builtin_bit_cast(bf16x8, frags[(192 + s * 2 + 1) * 64 + lane]);
            }
        }
    }
    const float bl = blin[0];
    float cst[4] = {0.f, 0.f, 0.f, 0.f};

    // hoisted LDS index bases (parity folds at compile time via unroll-2)
    const int baseA = (q * 4 + 4 * (l15 >> 1)) & 31;        // k-step even
    const int baseB = (baseA + 16) & 31;                    // k-step odd
    const int widx  = (((uc >> 1) + 4 * ((q * 4) >> 1)) & 31); // recomputed per r below

    __syncthreads();

#define ACT_STORE(DST_H, DST_L, PW, ACC)                                        \
    do {                                                                        \
        _Pragma("unroll")                                                       \
        for (int r = 0; r < 4; r++) {                                           \
            float si = sigm_s((ACC)[0][r]);                                     \
            float sf = sigm_s((ACC)[1][r]);                                     \
            float tg = tanh_s((ACC)[2][r]);                                     \
            float so = sigm_s((ACC)[3][r]);                                     \
            float cn = fmaf(sf, cst[r], si * tg);                               \
            cst[r] = cn;                                                        \
            float h = so * tanh_s(2.0f * L2E * cn);                             \
            unsigned hb = __float_as_uint(h);                                   \
            unsigned short hi = (unsigned short)(hb >> 16);                     \
            float lof = h - __uint_as_float(hb & 0xFFFF0000u);                  \
            unsigned short lo = (unsigned short)(__float_as_uint(lof) >> 16);   \
            int bb = q * 4 + r;                                                 \
            int wi = (((uc >> 1) + 4 * (bb >> 1)) & 31) * 2 + (uc & 1);         \
            ((unsigned short*)&DST_H[PW][bb][0])[wi] = hi;                      \
            ((unsigned short*)&DST_L[PW][bb][0])[wi] = lo;                      \
        }                                                                       \
    } while (0)

#define STEP(IT, P)                                                             \
    do {                                                                        \
        if (c2w) {                                                              \
            if ((IT) >= 1 && (IT) <= TT) {       /* cell2 -> h2(IT-1) */        \
                floatx4 d[4];                                                   \
                _Pragma("unroll")                                               \
                for (int g = 0; g < 4; g++)                                     \
                    d[g] = (floatx4){bcol[g], bcol[g], bcol[g], bcol[g]};       \
                _Pragma("unroll")                                               \
                for (int s = 0; s < 4; s++) {                                   \
                    int base = (s & 1) ? baseB : baseA;                         \
                    bf16x8 ah, al;                                              \
                    if (s < 2) { ah = *(const bf16x8*)&h1h[1 - (P)][l15][base]; \
                                 al = *(const bf16x8*)&h1l[1 - (P)][l15][base]; }\
                    else       { ah = *(const bf16x8*)&h2h[(P)][l15][base];     \
                                 al = *(const bf16x8*)&h2l[(P)][l15][base]; }   \
                    _Pragma("unroll")                                           \
                    for (int g = 0; g < 4; g++) {                               \
                        d[g] = MFMA16(ah, fr[g * 8 + s * 2 + 0], d[g]);         \
                        d[g] = MFMA16(ah, fr[g * 8 + s * 2 + 1], d[g]);         \
                        d[g] = MFMA16(al, fr[g * 8 + s * 2 + 0], d[g]);         \
                    }                                                           \
                }                                                               \
                ACT_STORE(h2h, h2l, 1 - (P), d);                                \
            }                                                                   \
        } else {                                                                \
            if ((IT) <= TT - 1) {                /* cell1 -> h1(IT) */          \
                float4 xv = *(const float4*)&xb[(IT) * 16 + q * 4];             \
                floatx4 a[4];                                                   \
                _Pragma("unroll")                                               \
                for (int g = 0; g < 4; g++) {                                   \
                    a[g][0] = fmaf(xv.x, wx[g], bcol[g]);                       \
                    a[g][1] = fmaf(xv.y, wx[g], bcol[g]);                       \
                    a[g][2] = fmaf(xv.z, wx[g], bcol[g]);                       \
                    a[g][3] = fmaf(xv.w, wx[g], bcol[g]);                       \
                }                                                               \
                _Pragma("unroll")                                               \
                for (int s = 0; s < 2; s++) {                                   \
                    int base = s ? baseB : baseA;                               \
                    bf16x8 ah = *(const bf16x8*)&h1h[1 - (P)][l15][base];       \
                    bf16x8 al = *(const bf16x8*)&h1l[1 - (P)][l15][base];       \
                    _Pragma("unroll")                                           \
                    for (int g = 0; g < 4; g++) {                               \
                        a[g] = MFMA16(ah, fr[g * 4 + s * 2 + 0], a[g]);         \
                        a[g] = MFMA16(ah, fr[g * 4 + s * 2 + 1], a[g]);         \
                        a[g] = MFMA16(al, fr[g * 4 + s * 2 + 0], a[g]);         \
                    }                                                           \
                }                                                               \
                ACT_STORE(h1h, h1l, (P), a);                                    \
            }                                                                   \
            if (w == 4 && (IT) >= 2) {           /* head -> out(IT-2) */        \
                floatx4 ho = {0.f, 0.f, 0.f, 0.f};                              \
                _Pragma("unroll")                                               \
                for (int s = 0; s < 2; s++) {                                   \
                    int base = s ? baseB : baseA;                               \
                    bf16x8 ah = *(const bf16x8*)&h2h[(P)][l15][base];           \
                    bf16x8 al = *(const bf16x8*)&h2l[(P)][l15][base];           \
                    ho = MFMA16(ah, fr[16 + s * 2 + 0], ho);                    \
                    ho = MFMA16(ah, fr[16 + s * 2 + 1], ho);                    \
                    ho = MFMA16(al, fr[16 + s * 2 + 0], ho);                    \
                }                                                               \
                if (l15 == 0) {                                                 \
                    _Pragma("unroll")                                           \
                    for (int r = 0; r < 4; r++)                                 \
                        out[(size_t)(b0g + q * 4 + r) * TT + ((IT) - 2)] = ho[r] + bl; \
                }                                                               \
            }                                                                   \
        }                                                                       \
        __syncthreads();                                                        \
    } while (0)

    for (int itp = 0; itp < TT + 2; itp += 2) {   // its 0..TT+1, parity baked
        STEP(itp, 0);
        STEP(itp + 1, 1);
    }
#undef STEP
#undef ACT_STORE
}

extern "C" void kernel_launch(void* const* d_in, const int* in_sizes, int n_in,
                              void* d_out, int out_size, void* d_ws, size_t ws_size,
                              hipStream_t stream) {
    const float* input = (const float*)d_in[0];
    const float* Wih1  = (const float*)d_in[1];
    const float* Whh1  = (const float*)d_in[2];
    const float* bih1  = (const float*)d_in[3];
    const float* bhh1  = (const float*)d_in[4];
    const float* Wih2  = (const float*)d_in[5];
    const float* Whh2  = (const float*)d_in[6];
    const float* bih2  = (const float*)d_in[7];
    const float* bhh2  = (const float*)d_in[8];
    const float* Wlin  = (const float*)d_in[9];
    const float* blin  = (const float*)d_in[10];

    uint4* frags = (uint4*)d_ws;            // 196 frags * 1 KiB
    int B = in_sizes[0] / TT;               // 4096

    lstm_prep<<<49, 256, 0, stream>>>(Whh1, Wih2, Whh2, Wlin, frags);
    lstm_main<<<B / NB, 512, 0, stream>>>(input, frags, Wih1, bih1, bhh1,
                                          bih2, bhh2, blin, (float*)d_out);
}